// Round 2
// baseline (10422.641 us; speedup 1.0000x reference)
//
#include <hip/hip_runtime.h>
#include <stdint.h>

typedef unsigned long long u64;

#define NBATCH 32
#define NPAIR  16                // batch pairs; pair p -> batches (p, p+16)
#define NPTS   131072
#define KBLK   16                // chunks (blocks) per batch
#define PPB    (NPTS / KBLK)     // 8192 points per chunk (2^13)
#define NTHR   1024
#define NWAVE  (NTHR / 64)       // 16 waves
#define PPT    (PPB / NTHR)      // 8 points per thread per batch
#define FLT_MAX_C 3.402823466e+38f

// ws: per (batch, chunk, parity) one 64B slot of 8 u64.
// words 0..2: ((u64)s<<32) | float_bits(x|y|z)   -- self-tagged, relaxed
// word  3   : ((u64)s<<49) | dist_bits<<17 | (131071-idx)
// 0xAA poison never matches s<2048 -> no ws init needed.
// Size: 32*16*2*64B = 64 KB.
__device__ __forceinline__ u64* slot_ptr(u64* slots, int b, int k, int par) {
    return slots + ((size_t)((b * KBLK + k) * 2 + par)) * 8;
}

// ---- scan one batch's 8 resident points: update md, local argmax ----------
#define SCAN(PX,PY,PZ,MD,CX,CY,CZ,BV,GI) do {                                  \
    float bv_ = -1.0f; int bp_ = 0;                                            \
    _Pragma("unroll")                                                          \
    for (int p = 0; p < PPT; ++p) {                                            \
        float dx = __fsub_rn(PX[p], CX);                                       \
        float dy = __fsub_rn(PY[p], CY);                                       \
        float dz = __fsub_rn(PZ[p], CZ);                                       \
        float d  = __fadd_rn(__fadd_rn(__fmul_rn(dx,dx), __fmul_rn(dy,dy)),    \
                             __fmul_rn(dz,dz));                                \
        float m  = fminf(MD[p], d);                                            \
        MD[p] = m;                                                             \
        bool tk = m > bv_;                                                     \
        bv_ = tk ? m : bv_;                                                    \
        bp_ = tk ? p : bp_;                                                    \
    }                                                                          \
    BV = bv_;                                                                  \
    GI = kk * PPB + ((bp_ >> 2) * (NTHR * 4)) + t4 + (bp_ & 3);                \
} while (0)

// ---- block reduce + publish di word + owner ships winner coords -----------
#define REDPUB(PX,PY,PZ,BX,SS,BV,GI) do {                                      \
    float bv_ = BV; int gi_ = GI;                                              \
    _Pragma("unroll")                                                          \
    for (int off = 32; off >= 1; off >>= 1) {                                  \
        float ov = __shfl_down(bv_, off);                                      \
        int   oi = __shfl_down(gi_, off);                                      \
        bool tk = (ov > bv_) || (ov == bv_ && oi < gi_);                       \
        bv_ = tk ? ov : bv_;                                                   \
        gi_ = tk ? oi : gi_;                                                   \
    }                                                                          \
    if (lane == 0) { s_v[wv] = bv_; s_i[wv] = gi_; }                           \
    __syncthreads();                                                           \
    if (wv == 0) {                                                             \
        float v16 = (lane < NWAVE) ? s_v[lane] : -1.0f;                        \
        int   i16 = (lane < NWAVE) ? s_i[lane] : 0x7fffffff;                   \
        _Pragma("unroll")                                                      \
        for (int off = 8; off >= 1; off >>= 1) {                               \
            float ov = __shfl_down(v16, off);                                  \
            int   oi = __shfl_down(i16, off);                                  \
            bool tk = (ov > v16) || (ov == v16 && oi < i16);                   \
            v16 = tk ? ov : v16;                                               \
            i16 = tk ? oi : i16;                                               \
        }                                                                      \
        if (lane == 0) {                                                       \
            u64 di = ((u64)(unsigned)(SS) << 49)                               \
                   | ((u64)__float_as_uint(v16) << 17)                         \
                   | (u64)(unsigned)(131071 - i16);                            \
            __hip_atomic_store(slot_ptr(slots, BX, kk, (SS) & 1) + 3, di,      \
                               __ATOMIC_RELAXED, __HIP_MEMORY_SCOPE_AGENT);    \
            s_bi = i16;                                                        \
        }                                                                      \
    }                                                                          \
    __syncthreads();                                                           \
    {                                                                          \
        int widx = s_bi;                                                       \
        if ((widx >> 13) == kk) {                                              \
            int l = widx & (PPB - 1);                                          \
            if (t == ((l >> 2) & (NTHR - 1))) {                                \
                int pw = ((l >> 12) << 2) | (l & 3);                           \
                float wx = 0.f, wy = 0.f, wz = 0.f;                            \
                _Pragma("unroll")                                              \
                for (int p = 0; p < PPT; ++p) {                                \
                    bool e = (p == pw);                                        \
                    wx = e ? PX[p] : wx;                                       \
                    wy = e ? PY[p] : wy;                                       \
                    wz = e ? PZ[p] : wz;                                       \
                }                                                              \
                u64 tg = (u64)(unsigned)(SS) << 32;                            \
                u64* sp = slot_ptr(slots, BX, kk, (SS) & 1);                   \
                __hip_atomic_store(sp + 0, tg | __float_as_uint(wx),           \
                                   __ATOMIC_RELAXED, __HIP_MEMORY_SCOPE_AGENT);\
                __hip_atomic_store(sp + 1, tg | __float_as_uint(wy),           \
                                   __ATOMIC_RELAXED, __HIP_MEMORY_SCOPE_AGENT);\
                __hip_atomic_store(sp + 2, tg | __float_as_uint(wz),           \
                                   __ATOMIC_RELAXED, __HIP_MEMORY_SCOPE_AGENT);\
            }                                                                  \
        }                                                                      \
    }                                                                          \
} while (0)

// ---- issue the poll loads early (latency hidden under other batch's scan) -
#define PREFETCH(BX, SS, PRE) do {                                             \
    if (wv == 0) {                                                             \
        u64* ps = slot_ptr(slots, BX, lane >> 2, (SS) & 1) + (lane & 3);       \
        PRE = __hip_atomic_load(ps, __ATOMIC_RELAXED,                          \
                                __HIP_MEMORY_SCOPE_AGENT);                     \
    }                                                                          \
} while (0)

// ---- complete poll (retry fallback), select winner, broadcast -------------
#define POLLSEL(BX, SS, PRE, SBC) do {                                         \
    if (wv == 0) {                                                             \
        u64* ps = slot_ptr(slots, BX, lane >> 2, (SS) & 1) + (lane & 3);       \
        const int sh = ((lane & 3) == 3) ? 49 : 32;                            \
        u64 got = PRE;                                                         \
        while ((int)(got >> sh) != (SS))                                       \
            got = __hip_atomic_load(ps, __ATOMIC_RELAXED,                      \
                                    __HIP_MEMORY_SCOPE_AGENT);                 \
        u64 dval = (u64)__shfl((long long)got, ((lane & 15) << 2) | 3);        \
        u64 dv = (lane < 16) ? dval : 0ull;                                    \
        _Pragma("unroll")                                                      \
        for (int off = 8; off >= 1; off >>= 1) {                               \
            u64 o = (u64)__shfl_down((long long)dv, off);                      \
            dv = (o > dv) ? o : dv;                                            \
        }                                                                      \
        u64 win = (u64)__shfl((long long)dv, 0);                               \
        u64 mask = __ballot(lane < 16 && dval == win);                         \
        int w = __ffsll(mask) - 1;                                             \
        unsigned lo = (unsigned)got;                                           \
        unsigned cxb = (unsigned)__shfl((int)lo, (w << 2) | 0);                \
        unsigned cyb = (unsigned)__shfl((int)lo, (w << 2) | 1);                \
        unsigned czb = (unsigned)__shfl((int)lo, (w << 2) | 2);                \
        int idx = 131071 - (int)(win & 0x1FFFF);                               \
        if (lane == 0) {                                                       \
            SBC[0] = cxb; SBC[1] = cyb; SBC[2] = czb;                          \
            if (kk == 0) out[(size_t)(BX) * S + (SS)] = idx;                   \
        }                                                                      \
    }                                                                          \
    __syncthreads();                                                           \
} while (0)

__global__ __launch_bounds__(NTHR, 4)   // 16-wave block, 1/CU: co-resident
void fps_kernel(const float* __restrict__ points, int* __restrict__ out,
                u64* __restrict__ slots, int S)
{
    const int pr   = blockIdx.x & (NPAIR - 1);   // pair id: chunks of a pair
    const int kk   = blockIdx.x >> 4;            // stay == pr (mod 8) -> XCD
    const int bA   = pr;
    const int bB   = pr + NPAIR;
    const int t    = threadIdx.x;
    const int lane = t & 63;
    const int wv   = t >> 6;
    const int t4   = t * 4;

    const float* pbA = points + (size_t)bA * 3 * NPTS;
    const float* pbB = points + (size_t)bB * 3 * NPTS;
    const float* bxA = pbA + kk * PPB;
    const float* byA = bxA + NPTS;
    const float* bzA = bxA + 2 * NPTS;
    const float* bxB = pbB + kk * PPB;
    const float* byB = bxB + NPTS;
    const float* bzB = bxB + 2 * NPTS;

    // 64 floats of persistent state per thread (two batches' chunks)
    float pxA[PPT], pyA[PPT], pzA[PPT], mdA[PPT];
    float pxB[PPT], pyB[PPT], pzB[PPT], mdB[PPT];
#pragma unroll
    for (int c = 0; c < PPT / 4; ++c) {
        float4 vx = *(const float4*)(bxA + c * (NTHR * 4) + t4);
        float4 vy = *(const float4*)(byA + c * (NTHR * 4) + t4);
        float4 vz = *(const float4*)(bzA + c * (NTHR * 4) + t4);
        pxA[c*4+0]=vx.x; pxA[c*4+1]=vx.y; pxA[c*4+2]=vx.z; pxA[c*4+3]=vx.w;
        pyA[c*4+0]=vy.x; pyA[c*4+1]=vy.y; pyA[c*4+2]=vy.z; pyA[c*4+3]=vy.w;
        pzA[c*4+0]=vz.x; pzA[c*4+1]=vz.y; pzA[c*4+2]=vz.z; pzA[c*4+3]=vz.w;
        mdA[c*4+0]=FLT_MAX_C; mdA[c*4+1]=FLT_MAX_C;
        mdA[c*4+2]=FLT_MAX_C; mdA[c*4+3]=FLT_MAX_C;
    }
#pragma unroll
    for (int c = 0; c < PPT / 4; ++c) {
        float4 vx = *(const float4*)(bxB + c * (NTHR * 4) + t4);
        float4 vy = *(const float4*)(byB + c * (NTHR * 4) + t4);
        float4 vz = *(const float4*)(bzB + c * (NTHR * 4) + t4);
        pxB[c*4+0]=vx.x; pxB[c*4+1]=vx.y; pxB[c*4+2]=vx.z; pxB[c*4+3]=vx.w;
        pyB[c*4+0]=vy.x; pyB[c*4+1]=vy.y; pyB[c*4+2]=vy.z; pyB[c*4+3]=vy.w;
        pzB[c*4+0]=vz.x; pzB[c*4+1]=vz.y; pzB[c*4+2]=vz.z; pzB[c*4+3]=vz.w;
        mdB[c*4+0]=FLT_MAX_C; mdB[c*4+1]=FLT_MAX_C;
        mdB[c*4+2]=FLT_MAX_C; mdB[c*4+3]=FLT_MAX_C;
    }

    __shared__ float    s_v[NWAVE];
    __shared__ int      s_i[NWAVE];
    __shared__ int      s_bi;
    __shared__ unsigned s_bcA[4];
    __shared__ unsigned s_bcB[4];

    float cxA = pbA[0], cyA = pbA[NPTS], czA = pbA[2 * NPTS];
    float cxB = pbB[0], cyB = pbB[NPTS], czB = pbB[2 * NPTS];
    if (kk == 0 && t == 0) {
        out[(size_t)bA * S] = 0;
        out[(size_t)bB * S] = 0;
    }

    u64 preA = 0, preB = 0;
    float bv; int gi;

    // Staggered two-batch pipeline: each batch's publish->poll fabric round
    // trip is covered by the OTHER batch's scan+reduce.
    for (int s = 1; s < S; ++s) {
        SCAN(pxA, pyA, pzA, mdA, cxA, cyA, czA, bv, gi);
        REDPUB(pxA, pyA, pzA, bA, s, bv, gi);

        if (s >= 2) {                       // B(s-1): published one half-cycle ago
            POLLSEL(bB, s - 1, preB, s_bcB);
            cxB = __uint_as_float(s_bcB[0]);
            cyB = __uint_as_float(s_bcB[1]);
            czB = __uint_as_float(s_bcB[2]);
        }

        SCAN(pxB, pyB, pzB, mdB, cxB, cyB, czB, bv, gi);
        PREFETCH(bA, s, preA);              // A(s) loads fly under reduce/publish B
        REDPUB(pxB, pyB, pzB, bB, s, bv, gi);

        POLLSEL(bA, s, preA, s_bcA);
        cxA = __uint_as_float(s_bcA[0]);
        cyA = __uint_as_float(s_bcA[1]);
        czA = __uint_as_float(s_bcA[2]);

        PREFETCH(bB, s, preB);              // B(s) loads fly across the backedge
    }

    // epilogue: B's final step result (no broadcast needed)
    {
        const int ss = S - 1;
        if (wv == 0) {
            u64* ps = slot_ptr(slots, bB, lane >> 2, ss & 1) + (lane & 3);
            const int sh = ((lane & 3) == 3) ? 49 : 32;
            u64 got = preB;
            while ((int)(got >> sh) != ss)
                got = __hip_atomic_load(ps, __ATOMIC_RELAXED,
                                        __HIP_MEMORY_SCOPE_AGENT);
            u64 dval = (u64)__shfl((long long)got, ((lane & 15) << 2) | 3);
            u64 dv = (lane < 16) ? dval : 0ull;
#pragma unroll
            for (int off = 8; off >= 1; off >>= 1) {
                u64 o = (u64)__shfl_down((long long)dv, off);
                dv = (o > dv) ? o : dv;
            }
            u64 win = (u64)__shfl((long long)dv, 0);
            int idx = 131071 - (int)(win & 0x1FFFF);
            if (lane == 0 && kk == 0) out[(size_t)bB * S + ss] = idx;
        }
    }
}

extern "C" void kernel_launch(void* const* d_in, const int* in_sizes, int n_in,
                              void* d_out, int out_size, void* d_ws, size_t ws_size,
                              hipStream_t stream) {
    const float* points = (const float*)d_in[0];
    int* out   = (int*)d_out;
    u64* slots = (u64*)d_ws;              // 32*16*2*64B = 64 KB
    int S = out_size / NBATCH;            // 2048
    // 16 pairs x 16 chunks = 256 blocks x 16 waves -> exactly 1 block/CU.
    fps_kernel<<<dim3(NPAIR * KBLK), dim3(NTHR), 0, stream>>>(points, out, slots, S);
}

// Round 8
// 7673.848 us; speedup vs baseline: 1.3582x; 1.3582x over previous
//
#include <hip/hip_runtime.h>
#include <stdint.h>

typedef unsigned long long u64;

#define NBATCH 32
#define NPTS   131072
#define KBLK   8                 // blocks per batch
#define PPB    (NPTS / KBLK)     // 16384 points per block (2^14)
#define NTHR   1024
#define NWAVE  (NTHR / 64)       // 16 waves
#define PPT    (PPB / NTHR)      // 16 points per thread
#define FLT_MAX_C 3.402823466e+38f

// ws: per (batch, block, parity) one 64B slot of 8 u64.
// words 0..2: ((u64)s<<32) | float_bits(x|y|z)   -- self-tagged, relaxed
// word  3   : ((u64)s<<49) | dist_bits<<17 | (131071-idx)
//   (dist>=0 -> float bits monotone as uint; idx inverted so u64-max gives
//    first-occurrence argmax, matching np.argmax tie-break.)
// 0xAA poison: tags 0xAAAAAAAA / 21845 never equal s<2048 -> no ws init.
__device__ __forceinline__ u64* slot_ptr(u64* slots, int b, int k, int par) {
    return slots + ((size_t)((b * KBLK + k) * 2 + par)) * 8;
}

__global__ __launch_bounds__(NTHR, 4)   // cap 128 VGPR: 16-wave block fits 1/CU
void fps_kernel(const float* __restrict__ points, int* __restrict__ out,
                u64* __restrict__ slots, int S)
{
    const int b    = blockIdx.x & (NBATCH - 1);
    const int kk   = blockIdx.x >> 5;
    const int t    = threadIdx.x;
    const int lane = t & 63;
    const int wv   = t >> 6;

    const float* pb = points + (size_t)b * 3 * NPTS;
    const float* bx = pb + kk * PPB;
    const float* by = bx + NPTS;
    const float* bz = bx + 2 * NPTS;

    // 64 floats of persistent state per thread -> real VGPRs (<=128 cap).
    float px[PPT], py[PPT], pz[PPT], md[PPT];
    const int t4 = t * 4;
#pragma unroll
    for (int c = 0; c < PPT / 4; ++c) {
        float4 vx = *(const float4*)(bx + c * (NTHR * 4) + t4);
        float4 vy = *(const float4*)(by + c * (NTHR * 4) + t4);
        float4 vz = *(const float4*)(bz + c * (NTHR * 4) + t4);
        px[c*4+0]=vx.x; px[c*4+1]=vx.y; px[c*4+2]=vx.z; px[c*4+3]=vx.w;
        py[c*4+0]=vy.x; py[c*4+1]=vy.y; py[c*4+2]=vy.z; py[c*4+3]=vy.w;
        pz[c*4+0]=vz.x; pz[c*4+1]=vz.y; pz[c*4+2]=vz.z; pz[c*4+3]=vz.w;
        md[c*4+0]=FLT_MAX_C; md[c*4+1]=FLT_MAX_C;
        md[c*4+2]=FLT_MAX_C; md[c*4+3]=FLT_MAX_C;
    }

    // per-wave winner: key = dist_bits<<17 | (131071-idx), plus coord bits
    __shared__ u64      s_wk[NWAVE];
    __shared__ unsigned s_wc[NWAVE][4];
    __shared__ unsigned s_bc[4];    // next centroid xbits,ybits,zbits (+pad)

    float cx = pb[0], cy = pb[NPTS], cz = pb[2 * NPTS];
    if (kk == 0 && t == 0) out[(size_t)b * S] = 0;

    for (int s = 1; s < S; ++s) {
        // ---- scan: exact np fp32 semantics (no fma), ascending-index '>'
        float bestv = -1.0f;
        int   bestp = 0;
#pragma unroll
        for (int p = 0; p < PPT; ++p) {
            float dx = __fsub_rn(px[p], cx);
            float dy = __fsub_rn(py[p], cy);
            float dz = __fsub_rn(pz[p], cz);
            float d  = __fadd_rn(__fadd_rn(__fmul_rn(dx, dx), __fmul_rn(dy, dy)),
                                 __fmul_rn(dz, dz));
            float m  = fminf(md[p], d);
            md[p] = m;
            bool tk = m > bestv;
            bestv = tk ? m : bestv;
            bestp = tk ? p : bestp;
        }
        int gidx = kk * PPB + (bestp >> 2) * (NTHR * 4) + t4 + (bestp & 3);

        // ---- butterfly wave reduce: ALL lanes learn the wave winner
        float wvv = bestv; int wvi = gidx;
#pragma unroll
        for (int off = 32; off >= 1; off >>= 1) {
            float ov = __shfl_xor(wvv, off);
            int   oi = __shfl_xor(wvi, off);
            bool tk = (ov > wvv) || (ov == wvv && oi < wvi);
            wvv = tk ? ov : wvv;
            wvi = tk ? oi : wvi;
        }
        // winner lane (unique: gidx unique per lane) self-extracts its coords
        if (bestv == wvv && gidx == wvi) {
            float wx = 0.f, wy = 0.f, wz = 0.f;
#pragma unroll
            for (int p = 0; p < PPT; ++p) {        // constant-index select
                bool e = (p == bestp);
                wx = e ? px[p] : wx; wy = e ? py[p] : wy; wz = e ? pz[p] : wz;
            }
            s_wk[wv] = ((u64)__float_as_uint(wvv) << 17)
                     | (u64)(unsigned)(131071 - wvi);
            s_wc[wv][0] = __float_as_uint(wx);
            s_wc[wv][1] = __float_as_uint(wy);
            s_wc[wv][2] = __float_as_uint(wz);
        }
        __syncthreads();                           // B1: s_wk/s_wc ready

        if (wv == 0) {
            const int q = lane >> 2, r = lane & 3;
            // cross-wave butterfly max over 16 keys (lanes 0-15 valid)
            u64 orig = (lane < NWAVE) ? s_wk[lane] : 0ull;
            u64 kmax = orig;
#pragma unroll
            for (int off = 8; off >= 1; off >>= 1) {
                u64 o = (u64)__shfl_xor((long long)kmax, off);
                kmax = (o > kmax) ? o : kmax;
            }
            u64 wmask = __ballot(lane < NWAVE && orig == kmax);
            int wstar = __ffsll(wmask) - 1;        // wave-uniform

            // build all 4 publish words; lanes 0-3 store 32B coalesced
            unsigned cb = s_wc[wstar][r];
            u64 pubw = (r == 3)
                ? (((u64)(unsigned)s << 49) | kmax)
                : (((u64)(unsigned)s << 32) | (u64)cb);
            if (lane < 4)
                __hip_atomic_store(slot_ptr(slots, b, kk, s & 1) + r, pubw,
                                   __ATOMIC_RELAXED, __HIP_MEMORY_SCOPE_AGENT);
            // own block's words via shfl -- skip the self MALL roundtrip
            u64 ownw = (u64)__shfl((long long)pubw, r);

            // poll remote blocks only, pipelined spin (1 load in flight)
            u64 got = 0;
            if (lane < 4 * KBLK && q != kk) {
                u64* ps = slot_ptr(slots, b, q, s & 1) + r;
                const int sh = (r == 3) ? 49 : 32;
                u64 a  = __hip_atomic_load(ps, __ATOMIC_RELAXED,
                                           __HIP_MEMORY_SCOPE_AGENT);
                u64 nx = __hip_atomic_load(ps, __ATOMIC_RELAXED,
                                           __HIP_MEMORY_SCOPE_AGENT);
                while ((int)(a >> sh) != s) {
                    a  = nx;
                    nx = __hip_atomic_load(ps, __ATOMIC_RELAXED,
                                           __HIP_MEMORY_SCOPE_AGENT);
                }
                got = a;
            }
            if (q == kk) got = ownw;

            // select winning block by u64-max of di words (unique in low bits)
            u64 dval = (u64)__shfl((long long)got, ((lane & 7) << 2) | 3);
            u64 dv = (lane < KBLK) ? dval : 0ull;
#pragma unroll
            for (int off = 4; off >= 1; off >>= 1) {
                u64 o = (u64)__shfl_down((long long)dv, off);
                dv = (o > dv) ? o : dv;
            }
            u64 win = (u64)__shfl((long long)dv, 0);
            u64 bmask = __ballot(lane < KBLK && dval == win);
            int w = __ffsll(bmask) - 1;
            unsigned lo = (unsigned)got;
            unsigned cxb = (unsigned)__shfl((int)lo, (w << 2) | 0);
            unsigned cyb = (unsigned)__shfl((int)lo, (w << 2) | 1);
            unsigned czb = (unsigned)__shfl((int)lo, (w << 2) | 2);
            int idx = 131071 - (int)(win & 0x1FFFF);
            if (lane == 0) {
                s_bc[0] = cxb; s_bc[1] = cyb; s_bc[2] = czb;
                if (kk == 0) out[(size_t)b * S + s] = idx;
            }
        }
        __syncthreads();                           // B2: s_bc ready
        cx = __uint_as_float(s_bc[0]);
        cy = __uint_as_float(s_bc[1]);
        cz = __uint_as_float(s_bc[2]);
    }
}

extern "C" void kernel_launch(void* const* d_in, const int* in_sizes, int n_in,
                              void* d_out, int out_size, void* d_ws, size_t ws_size,
                              hipStream_t stream) {
    const float* points = (const float*)d_in[0];
    int* out   = (int*)d_out;
    u64* slots = (u64*)d_ws;              // 32*8*2*64B = 32 KB
    int S = out_size / NBATCH;            // 2048
    // 256 blocks x 16 waves -> exactly 1 block/CU on 256 CUs: co-resident.
    fps_kernel<<<dim3(NBATCH * KBLK), dim3(NTHR), 0, stream>>>(points, out, slots, S);
}

// Round 11
// 5907.512 us; speedup vs baseline: 1.7643x; 1.2990x over previous
//
#include <hip/hip_runtime.h>
#include <stdint.h>

typedef unsigned long long u64;

#define NBATCH 32
#define NPTS   131072
#define KBLK   8                 // blocks per batch
#define PPB    (NPTS / KBLK)     // 16384 points per block (2^14)
#define NTHR   1024
#define NWAVE  (NTHR / 64)       // 16 waves
#define PPT    (PPB / NTHR)      // 16 points per thread
#define FLT_MAX_C 3.402823466e+38f

// ws: per (batch, block, parity) ONE u64 di word:
//   ((u64)s<<49) | dist_bits<<17 | (131071-idx)
//   dist>=0 -> float bits monotone as uint (sign=0 -> top bit <= 30, so
//   dist_bits<<17 tops out at bit 47, never touching the tag at bit 49).
//   idx inverted so u64-max gives first-occurrence argmax (np tie-break).
// Centroid coords are NOT shipped: blocks re-gather them from points[]
// (MALL-resident; bit-identical to the reference gather).
// Harness re-poisons ws (0xAA) each launch: tag 0x5555... never == s<2048,
// so no init pass and no cross-launch ABA. Size: 32*8*2*8B = 4 KB.
__device__ __forceinline__ u64* slot_ptr(u64* slots, int b, int k, int par) {
    return slots + (((b * KBLK + k) << 1) | par);
}
__device__ __forceinline__ u64 ld_slot(const u64* p) {
    return __hip_atomic_load(p, __ATOMIC_RELAXED, __HIP_MEMORY_SCOPE_AGENT);
}

__global__ __launch_bounds__(NTHR, 4)   // cap 128 VGPR: 16-wave block fits 1/CU
void fps_kernel(const float* __restrict__ points, int* __restrict__ out,
                u64* __restrict__ slots, int S)
{
    const int b    = blockIdx.x & (NBATCH - 1);
    const int kk   = blockIdx.x >> 5;
    const int t    = threadIdx.x;
    const int lane = t & 63;
    const int wv   = t >> 6;
    const int t4   = t * 4;

    const float* pb = points + (size_t)b * 3 * NPTS;
    const float* bx = pb + kk * PPB;
    const float* by = bx + NPTS;
    const float* bz = bx + 2 * NPTS;

    // 64 floats of persistent state per thread -> real VGPRs (<=128 cap).
    // Verbatim R8 layout: point p = c*4+j at px[p]; global idx
    // kk*PPB + c*(NTHR*4) + t*4 + j.
    float px[PPT], py[PPT], pz[PPT], md[PPT];
#pragma unroll
    for (int c = 0; c < PPT / 4; ++c) {
        float4 vx = *(const float4*)(bx + c * (NTHR * 4) + t4);
        float4 vy = *(const float4*)(by + c * (NTHR * 4) + t4);
        float4 vz = *(const float4*)(bz + c * (NTHR * 4) + t4);
        px[c*4+0]=vx.x; px[c*4+1]=vx.y; px[c*4+2]=vx.z; px[c*4+3]=vx.w;
        py[c*4+0]=vy.x; py[c*4+1]=vy.y; py[c*4+2]=vy.z; py[c*4+3]=vy.w;
        pz[c*4+0]=vz.x; pz[c*4+1]=vz.y; pz[c*4+2]=vz.z; pz[c*4+3]=vz.w;
        md[c*4+0]=FLT_MAX_C; md[c*4+1]=FLT_MAX_C;
        md[c*4+2]=FLT_MAX_C; md[c*4+3]=FLT_MAX_C;
    }

    __shared__ u64   s_wk[NWAVE];   // per-wave winner key
    __shared__ float s_bcf[4];      // next centroid x,y,z

    float cx = pb[0], cy = pb[NPTS], cz = pb[2 * NPTS];
    if (kk == 0 && t == 0) out[(size_t)b * S] = 0;

    for (int s = 1; s < S; ++s) {
        // ---- scan: exact np fp32 semantics (verbatim R8: no fma, rn per op)
        float bestv = -1.0f;
        int   bestp = 0;
#pragma unroll
        for (int p = 0; p < PPT; ++p) {
            float dx = __fsub_rn(px[p], cx);
            float dy = __fsub_rn(py[p], cy);
            float dz = __fsub_rn(pz[p], cz);
            float d  = __fadd_rn(__fadd_rn(__fmul_rn(dx, dx), __fmul_rn(dy, dy)),
                                 __fmul_rn(dz, dz));
            float m  = fminf(md[p], d);
            md[p] = m;
            bool tk = m > bestv;
            bestv = tk ? m : bestv;
            bestp = tk ? p : bestp;
        }
        int gidx = kk * PPB + (bestp >> 2) * (NTHR * 4) + t4 + (bestp & 3);

        // ---- wave reduce (verbatim R8 comparator), result in lane 0
        float bv = bestv; int bi = gidx;
#pragma unroll
        for (int off = 32; off >= 1; off >>= 1) {
            float ov = __shfl_down(bv, off);
            int   oi = __shfl_down(bi, off);
            bool tk = (ov > bv) || (ov == bv && oi < bi);
            bv = tk ? ov : bv;
            bi = tk ? oi : bi;
        }
        if (lane == 0)
            s_wk[wv] = ((u64)__float_as_uint(bv) << 17)
                     | (u64)(unsigned)(131071 - bi);
        __syncthreads();                           // B1: s_wk ready

        if (wv == 0) {
            // cross-wave butterfly over 16 keys (lanes 0-15 valid)
            u64 orig = (lane < NWAVE) ? s_wk[lane] : 0ull;
            u64 kmax = orig;
#pragma unroll
            for (int off = 8; off >= 1; off >>= 1) {
                u64 o = (u64)__shfl_xor((long long)kmax, off);
                kmax = (o > kmax) ? o : kmax;
            }
            u64 mydi = ((u64)(unsigned)s << 49) | kmax;
            // publish via atomic swap: RMW executes at the coherence point
            if (lane == 0)
                (void)__hip_atomic_exchange(slot_ptr(slots, b, kk, s & 1),
                                            mydi, __ATOMIC_RELAXED,
                                            __HIP_MEMORY_SCOPE_AGENT);

            // poll: lane k watches block k's di word (own block from regs)
            u64 got = mydi;
            if (lane < KBLK && lane != kk) {
                u64* ps = slot_ptr(slots, b, lane, s & 1);
                u64 a  = ld_slot(ps);
                u64 nx = ld_slot(ps);
                while ((int)(a >> 49) != s) {      // 2-deep pipelined spin
                    a  = nx;
                    nx = ld_slot(ps);
                }
                got = a;
            }
            // cross-block butterfly max (tags all == s -> payload order)
            u64 win = (lane < KBLK) ? got : 0ull;
#pragma unroll
            for (int off = 4; off >= 1; off >>= 1) {
                u64 o = (u64)__shfl_xor((long long)win, off);
                win = (o > win) ? o : win;
            }
            int idx = 131071 - (int)(win & 0x1FFFF);
            // centroid coords straight from points[] -- exact reference bits
            if (lane < 3) s_bcf[lane] = pb[(size_t)lane * NPTS + idx];
            if (lane == 0 && kk == 0) out[(size_t)b * S + s] = idx;
        }
        __syncthreads();                           // B2: s_bcf ready
        cx = s_bcf[0];
        cy = s_bcf[1];
        cz = s_bcf[2];
    }
}

extern "C" void kernel_launch(void* const* d_in, const int* in_sizes, int n_in,
                              void* d_out, int out_size, void* d_ws, size_t ws_size,
                              hipStream_t stream) {
    const float* points = (const float*)d_in[0];
    int* out   = (int*)d_out;
    u64* slots = (u64*)d_ws;              // 32*8*2*8B = 4 KB
    int S = out_size / NBATCH;            // 2048
    // 256 blocks x 16 waves -> exactly 1 block/CU on 256 CUs: co-resident.
    fps_kernel<<<dim3(NBATCH * KBLK), dim3(NTHR), 0, stream>>>(points, out, slots, S);
}